// Round 2
// baseline (338.295 us; speedup 1.0000x reference)
//
#include <hip/hip_runtime.h>

// Problem constants
#define NT 524288          // tokens
#define NE 64              // experts
#define NK 8               // top-k
#define TPB 128            // tokens per block (kernel 1 / 3's granularity)
#define NBLK (NT / TPB)    // 4096 blocks
#define SPB (TPB * NK)     // 1024 slots per block

// ---------------------------------------------------------------------------
// Kernel 1: per-token softmax + top-8 (lax.top_k semantics: descending value,
// ties -> smaller index), logits passthrough, and per-block expert histogram.
// Phase B (ranking) is NOT materialized here: kernel 3 recomputes the stable
// in-block ranks from out_assign, so K1 only needs per-block COUNTS.
// Block = 256 threads = 4 waves. 8 lanes per token, 8 logits per lane.
// Slot order within a block: slot_l = pass*256 + t (token-major), which is
// exactly the tile order the ballot counting processes.
// ---------------------------------------------------------------------------
__global__ __launch_bounds__(256) void topk_kernel(
    const float* __restrict__ logits,
    float* __restrict__ out_scores,
    float* __restrict__ out_assign,
    float* __restrict__ out_logits,
    int* __restrict__ blockCounts)      // ws: [NBLK][64]
{
    __shared__ int wcnt[4][NE];          // 1 KB

    const int t = threadIdx.x;
    const int b = blockIdx.x;
    const int g = t & 7;                 // lane within 8-lane token group
    const int tok_in_pass = t >> 3;      // 0..31
    const int w = t >> 6;                // wave 0..3
    const int l = t & 63;                // lane
    const unsigned long long lt_mask = (l == 0) ? 0ull : ((~0ull) >> (64 - l));

    int myCount = 0;                     // per-expert accumulator (t < NE)

    for (int pass = 0; pass < 4; ++pass) {
        const int ltok = pass * 32 + tok_in_pass;       // 0..127
        const int token = b * TPB + ltok;
        const float* lp = logits + (size_t)token * NE + g * 8;
        float4 v0 = *(const float4*)lp;
        float4 v1 = *(const float4*)(lp + 4);
        // passthrough copy
        float* op = out_logits + (size_t)token * NE + g * 8;
        *(float4*)op = v0;
        *(float4*)(op + 4) = v1;

        float lv[8] = {v0.x, v0.y, v0.z, v0.w, v1.x, v1.y, v1.z, v1.w};

        // softmax: max over 64 (local 8 + 3-step shuffle within group)
        float m = lv[0];
        #pragma unroll
        for (int j = 1; j < 8; ++j) m = fmaxf(m, lv[j]);
        #pragma unroll
        for (int sh = 1; sh < 8; sh <<= 1) m = fmaxf(m, __shfl_xor(m, sh, 64));

        float p[8];
        float s = 0.f;
        #pragma unroll
        for (int j = 0; j < 8; ++j) { p[j] = expf(lv[j] - m); s += p[j]; }
        #pragma unroll
        for (int sh = 1; sh < 8; sh <<= 1) s += __shfl_xor(s, sh, 64);
        #pragma unroll
        for (int j = 0; j < 8; ++j) p[j] = p[j] / s;   // IEEE div, match ref

        // iterative top-8 on probs; tie -> smaller global index
        float sc = 0.f; int id = 0;
        #pragma unroll
        for (int k = 0; k < NK; ++k) {
            float bv = p[0]; int bi = 0;
            #pragma unroll
            for (int j = 1; j < 8; ++j)
                if (p[j] > bv) { bv = p[j]; bi = j; }   // strict > keeps low idx
            int bidx = g * 8 + bi;
            #pragma unroll
            for (int sh = 1; sh < 8; sh <<= 1) {
                float ov = __shfl_xor(bv, sh, 64);
                int   oi = __shfl_xor(bidx, sh, 64);
                if (ov > bv || (ov == bv && oi < bidx)) { bv = ov; bidx = oi; }
            }
            if (g == k) { sc = bv; id = bidx; }
            if ((bidx >> 3) == g) p[bidx & 7] = -1.0f;  // kill winner
        }

        const size_t slot = (size_t)token * NK + g;     // coalesced
        out_scores[slot] = sc;
        out_assign[slot] = (float)id;

        // ---- fused histogram (counting only, no rank materialization) ----
        const int e = id;
        unsigned long long mask = ~0ull;
        #pragma unroll
        for (int bit = 0; bit < 6; ++bit) {
            unsigned long long bb = __ballot((e >> bit) & 1);
            mask &= ((e >> bit) & 1) ? bb : ~bb;
        }
        wcnt[w][l] = 0;                  // covers all 4x64 entries
        __syncthreads();
        if ((mask & lt_mask) == 0ull) wcnt[w][e] = __popcll(mask);  // leader
        __syncthreads();
        if (t < NE) myCount += wcnt[0][t] + wcnt[1][t] + wcnt[2][t] + wcnt[3][t];
        __syncthreads();                 // protect wcnt re-zero next pass
    }

    if (t < NE) blockCounts[b * NE + t] = myCount;
}

// ---------------------------------------------------------------------------
// Kernel 2: per-expert exclusive prefix sum over the 4096 block histograms
// (in place -> block starts). One block per expert. Totals -> counts output.
// ---------------------------------------------------------------------------
__global__ __launch_bounds__(256) void scan_kernel(
    int* __restrict__ blockCounts, float* __restrict__ out_counts)
{
    __shared__ int sdata[256];
    const int e = blockIdx.x;            // 0..63
    const int t = threadIdx.x;           // 0..255
    const int PER = NBLK / 256;          // 16

    int s = 0;
    for (int i = 0; i < PER; ++i) s += blockCounts[(t * PER + i) * NE + e];
    sdata[t] = s;
    __syncthreads();

    // Hillis-Steele inclusive scan over 256 partials
    for (int off = 1; off < 256; off <<= 1) {
        int v = (t >= off) ? sdata[t - off] : 0;
        __syncthreads();
        sdata[t] += v;
        __syncthreads();
    }
    int run = (t == 0) ? 0 : sdata[t - 1];

    for (int i = 0; i < PER; ++i) {
        const int idx = (t * PER + i) * NE + e;
        const int c = blockCounts[idx];
        blockCounts[idx] = run;          // exclusive start for this block
        run += c;
    }
    if (t == 255) out_counts[e] = (float)sdata[255];
}

// ---------------------------------------------------------------------------
// Kernel 3: recompute stable in-block ranks from out_assign (same ballot
// trick as K1, fully deterministic) seeded with the scanned block starts,
// and write final offsets. Traffic: 16.8 MB read + 16.8 MB write.
// ---------------------------------------------------------------------------
__global__ __launch_bounds__(256) void offs_kernel(
    const int* __restrict__ blockCounts,
    const float* __restrict__ out_assign,
    float* __restrict__ out_offs)
{
    __shared__ int running[NE];
    __shared__ int wcnt[4][NE];
    const int b = blockIdx.x;
    const int t = threadIdx.x;
    const int w = t >> 6;                // wave 0..3
    const int l = t & 63;                // lane
    const unsigned long long lt_mask = (l == 0) ? 0ull : ((~0ull) >> (64 - l));

    if (t < NE) running[t] = blockCounts[b * NE + t];   // global starts

    #pragma unroll
    for (int tile = 0; tile < 4; ++tile) {
        const int gslot = b * SPB + tile * 256 + t;     // token-major order
        const int e = (int)out_assign[gslot];

        // 6-bit radix ballot match: mask of lanes with same expert
        unsigned long long mask = ~0ull;
        #pragma unroll
        for (int bit = 0; bit < 6; ++bit) {
            unsigned long long bb = __ballot((e >> bit) & 1);
            mask &= ((e >> bit) & 1) ? bb : ~bb;
        }
        const int r_in_wave = __popcll(mask & lt_mask);
        const int wc = __popcll(mask);

        wcnt[w][l] = 0;                  // covers all 4x64 entries
        __syncthreads();                 // (also covers initial running[] init)
        if ((mask & lt_mask) == 0ull) wcnt[w][e] = wc;   // group leader
        __syncthreads();

        int before = running[e];
        for (int w2 = 0; w2 < w; ++w2) before += wcnt[w2][e];
        out_offs[gslot] = (float)(before + r_in_wave);

        __syncthreads();
        if (t < NE) running[t] += wcnt[0][t] + wcnt[1][t] + wcnt[2][t] + wcnt[3][t];
        __syncthreads();
    }
}

extern "C" void kernel_launch(void* const* d_in, const int* in_sizes, int n_in,
                              void* d_out, int out_size, void* d_ws, size_t ws_size,
                              hipStream_t stream) {
    // inputs: [0] expert_counts placeholder, [1] assignments placeholder,
    //         [2] offsets placeholder, [3] logits [NT, NE] float32
    const float* logits = (const float*)d_in[3];

    float* out = (float*)d_out;
    float* out_counts = out;                                   // [64]
    float* out_scores = out + NE;                              // [NT*NK]
    float* out_assign = out_scores + (size_t)NT * NK;          // [NT*NK]
    float* out_offs   = out_assign + (size_t)NT * NK;          // [NT*NK]
    float* out_logits = out_offs + (size_t)NT * NK;            // [NT*NE]

    int* blockCounts = (int*)d_ws;                             // 4096*64*4 = 1 MB

    hipLaunchKernelGGL(topk_kernel, dim3(NBLK), dim3(256), 0, stream,
                       logits, out_scores, out_assign, out_logits, blockCounts);
    hipLaunchKernelGGL(scan_kernel, dim3(NE), dim3(256), 0, stream,
                       blockCounts, out_counts);
    hipLaunchKernelGGL(offs_kernel, dim3(NBLK), dim3(256), 0, stream,
                       blockCounts, out_assign, out_offs);
}

// Round 3
// 328.574 us; speedup vs baseline: 1.0296x; 1.0296x over previous
//
#include <hip/hip_runtime.h>

// Problem constants
#define NT 524288          // tokens
#define NE 64              // experts
#define NK 8               // top-k
#define TPB 128            // tokens per block
#define NBLK (NT / TPB)    // 4096 blocks
#define SPB (TPB * NK)     // 1024 slots per block

// ---------------------------------------------------------------------------
// Kernel 1: softmax + top-8 + logits passthrough + per-block expert counts.
// TWO barriers total. The 4 passes are barrier-free straight-line code so
// loads/stores of different passes overlap. Histogram: ballot-match leaders
// atomicAdd into per-wave LDS rows (distinct addresses within a wave;
// atomicity protects cross-pass accumulation -> no ordering barriers needed).
// blockCounts layout is TRANSPOSED: [expert][block] so K2 is coalesced.
// ---------------------------------------------------------------------------
__global__ __launch_bounds__(256, 4) void topk_kernel(
    const float* __restrict__ logits,
    float* __restrict__ out_scores,
    float* __restrict__ out_assign,
    float* __restrict__ out_logits,
    int* __restrict__ blockCounts)      // ws: [NE][NBLK]
{
    __shared__ int wcnt[4][NE];          // 1 KB, per-wave histogram rows

    const int t = threadIdx.x;
    const int b = blockIdx.x;
    const int g = t & 7;                 // lane within 8-lane token group
    const int tok_in_pass = t >> 3;      // 0..31
    const int w = t >> 6;                // wave 0..3
    const int l = t & 63;                // lane
    const unsigned long long lt_mask = (l == 0) ? 0ull : ((~0ull) >> (64 - l));

    wcnt[w][l] = 0;                      // covers all 4x64 entries
    __syncthreads();                     // barrier 1

    #pragma unroll
    for (int pass = 0; pass < 4; ++pass) {
        const int ltok = pass * 32 + tok_in_pass;       // 0..127
        const int token = b * TPB + ltok;
        const float* lp = logits + (size_t)token * NE + g * 8;
        float4 v0 = *(const float4*)lp;
        float4 v1 = *(const float4*)(lp + 4);
        // passthrough copy
        float* op = out_logits + (size_t)token * NE + g * 8;
        *(float4*)op = v0;
        *(float4*)(op + 4) = v1;

        float lv[8] = {v0.x, v0.y, v0.z, v0.w, v1.x, v1.y, v1.z, v1.w};

        // softmax: max over 64 (local 8 + 3-step shuffle within group of 8)
        float m = lv[0];
        #pragma unroll
        for (int j = 1; j < 8; ++j) m = fmaxf(m, lv[j]);
        #pragma unroll
        for (int sh = 1; sh < 8; sh <<= 1) m = fmaxf(m, __shfl_xor(m, sh, 64));

        float p[8];
        float s = 0.f;
        #pragma unroll
        for (int j = 0; j < 8; ++j) { p[j] = expf(lv[j] - m); s += p[j]; }
        #pragma unroll
        for (int sh = 1; sh < 8; sh <<= 1) s += __shfl_xor(s, sh, 64);
        #pragma unroll
        for (int j = 0; j < 8; ++j) p[j] = p[j] / s;   // IEEE div, match ref

        // iterative top-8 on probs; tie -> smaller global index
        float sc = 0.f; int id = 0;
        #pragma unroll
        for (int k = 0; k < NK; ++k) {
            float bv = p[0]; int bi = 0;
            #pragma unroll
            for (int j = 1; j < 8; ++j)
                if (p[j] > bv) { bv = p[j]; bi = j; }   // strict > keeps low idx
            int bidx = g * 8 + bi;
            #pragma unroll
            for (int sh = 1; sh < 8; sh <<= 1) {
                float ov = __shfl_xor(bv, sh, 64);
                int   oi = __shfl_xor(bidx, sh, 64);
                if (ov > bv || (ov == bv && oi < bidx)) { bv = ov; bidx = oi; }
            }
            if (g == k) { sc = bv; id = bidx; }
            if ((bidx >> 3) == g) p[bidx & 7] = -1.0f;  // kill winner
        }

        const size_t slot = (size_t)token * NK + g;     // coalesced
        out_scores[slot] = sc;
        out_assign[slot] = (float)id;

        // histogram: ballot-match, leader accumulates its group's count
        const int e = id;
        unsigned long long mask = ~0ull;
        #pragma unroll
        for (int bit = 0; bit < 6; ++bit) {
            unsigned long long bb = __ballot((e >> bit) & 1);
            mask &= ((e >> bit) & 1) ? bb : ~bb;
        }
        if ((mask & lt_mask) == 0ull)
            atomicAdd(&wcnt[w][e], __popcll(mask));     // leader only
    }

    __syncthreads();                     // barrier 2
    if (t < NE) {
        const int c = wcnt[0][t] + wcnt[1][t] + wcnt[2][t] + wcnt[3][t];
        blockCounts[t * NBLK + b] = c;   // transposed layout
    }
}

// ---------------------------------------------------------------------------
// Kernel 2: per-expert exclusive prefix sum over 4096 block counts
// (in place -> block starts). One block per expert; transposed layout makes
// every global access fully coalesced. LDS staging padded (j + j/16) to
// avoid 16-int-stride bank conflicts. Totals -> counts output.
// ---------------------------------------------------------------------------
__global__ __launch_bounds__(256) void scan_kernel(
    int* __restrict__ blockCounts, float* __restrict__ out_counts)
{
    __shared__ int buf[NBLK + (NBLK >> 4)];   // 4352 ints = 17 KB
    __shared__ int part[256];
    const int e = blockIdx.x;            // 0..63
    const int t = threadIdx.x;           // 0..255
    int* col = blockCounts + (size_t)e * NBLK;

    #pragma unroll
    for (int i = 0; i < 16; ++i) {
        const int j = i * 256 + t;       // coalesced global read
        buf[j + (j >> 4)] = col[j];
    }
    __syncthreads();

    int loc[16];
    int s = 0;
    #pragma unroll
    for (int i = 0; i < 16; ++i) {       // thread t owns blocks [16t, 16t+16)
        const int j = t * 16 + i;
        loc[i] = s;
        s += buf[j + (j >> 4)];
    }
    part[t] = s;
    __syncthreads();

    // Hillis-Steele inclusive scan over 256 partials
    for (int off = 1; off < 256; off <<= 1) {
        int v = (t >= off) ? part[t - off] : 0;
        __syncthreads();
        part[t] += v;
        __syncthreads();
    }
    const int run = (t == 0) ? 0 : part[t - 1];

    #pragma unroll
    for (int i = 0; i < 16; ++i) {
        const int j = t * 16 + i;
        buf[j + (j >> 4)] = run + loc[i];    // exclusive start per block
    }
    __syncthreads();
    #pragma unroll
    for (int i = 0; i < 16; ++i) {
        const int j = i * 256 + t;
        col[j] = buf[j + (j >> 4)];      // coalesced global write
    }
    if (t == 255) out_counts[e] = (float)part[255];
}

// ---------------------------------------------------------------------------
// Kernel 3: recompute stable in-block ranks from out_assign and write final
// offsets. TWO barriers. All 4 tiles loaded first (masks kept in registers),
// leaders atomic-accumulate cnt[tile][wave][e], one barrier, then all ranks
// computed as LDS prefix sums and streamed out.
// ---------------------------------------------------------------------------
__global__ __launch_bounds__(256, 4) void offs_kernel(
    const int* __restrict__ blockCounts,   // [NE][NBLK] scanned starts
    const float* __restrict__ out_assign,
    float* __restrict__ out_offs)
{
    __shared__ int cnt[4][4][NE];        // [tile][wave][expert], 4 KB
    __shared__ int base[NE];
    const int t = threadIdx.x;
    const int b = blockIdx.x;
    const int w = t >> 6;                // wave 0..3
    const int l = t & 63;                // lane
    const unsigned long long lt_mask = (l == 0) ? 0ull : ((~0ull) >> (64 - l));

    #pragma unroll
    for (int tau = 0; tau < 4; ++tau) cnt[tau][w][l] = 0;
    if (t < NE) base[t] = blockCounts[t * NBLK + b];
    __syncthreads();                     // barrier 1

    int e_r[4];
    unsigned long long mask_r[4];
    #pragma unroll
    for (int tau = 0; tau < 4; ++tau) {
        const int gslot = b * SPB + tau * 256 + t;     // token-major order
        const int e = (int)out_assign[gslot];
        e_r[tau] = e;
        unsigned long long mask = ~0ull;
        #pragma unroll
        for (int bit = 0; bit < 6; ++bit) {
            unsigned long long bb = __ballot((e >> bit) & 1);
            mask &= ((e >> bit) & 1) ? bb : ~bb;
        }
        mask_r[tau] = mask;
        if ((mask & lt_mask) == 0ull)
            atomicAdd(&cnt[tau][w][e], __popcll(mask));  // leader only
    }
    __syncthreads();                     // barrier 2

    #pragma unroll
    for (int tau = 0; tau < 4; ++tau) {
        const int e = e_r[tau];
        int before = base[e];
        #pragma unroll
        for (int tau2 = 0; tau2 < 4; ++tau2)
            if (tau2 < tau)
                before += cnt[tau2][0][e] + cnt[tau2][1][e]
                        + cnt[tau2][2][e] + cnt[tau2][3][e];
        if (w > 0) before += cnt[tau][0][e];
        if (w > 1) before += cnt[tau][1][e];
        if (w > 2) before += cnt[tau][2][e];
        const int gslot = b * SPB + tau * 256 + t;
        out_offs[gslot] = (float)(before + __popcll(mask_r[tau] & lt_mask));
    }
}

extern "C" void kernel_launch(void* const* d_in, const int* in_sizes, int n_in,
                              void* d_out, int out_size, void* d_ws, size_t ws_size,
                              hipStream_t stream) {
    // inputs: [0] expert_counts placeholder, [1] assignments placeholder,
    //         [2] offsets placeholder, [3] logits [NT, NE] float32
    const float* logits = (const float*)d_in[3];

    float* out = (float*)d_out;
    float* out_counts = out;                                   // [64]
    float* out_scores = out + NE;                              // [NT*NK]
    float* out_assign = out_scores + (size_t)NT * NK;          // [NT*NK]
    float* out_offs   = out_assign + (size_t)NT * NK;          // [NT*NK]
    float* out_logits = out_offs + (size_t)NT * NK;            // [NT*NE]

    int* blockCounts = (int*)d_ws;                             // 64*4096*4 = 1 MB

    hipLaunchKernelGGL(topk_kernel, dim3(NBLK), dim3(256), 0, stream,
                       logits, out_scores, out_assign, out_logits, blockCounts);
    hipLaunchKernelGGL(scan_kernel, dim3(NE), dim3(256), 0, stream,
                       blockCounts, out_counts);
    hipLaunchKernelGGL(offs_kernel, dim3(NBLK), dim3(256), 0, stream,
                       blockCounts, out_assign, out_offs);
}

// Round 4
// 328.051 us; speedup vs baseline: 1.0312x; 1.0016x over previous
//
#include <hip/hip_runtime.h>

// Problem constants
#define NT 524288          // tokens
#define NE 64              // experts
#define NK 8               // top-k
#define TPB 128            // tokens per block
#define NBLK (NT / TPB)    // 4096 blocks
#define SPB (TPB * NK)     // 1024 slots per block

// ---------------------------------------------------------------------------
// Kernel 1: softmax + top-8 + logits passthrough + per-block expert counts.
// TWO barriers total; 4 barrier-free passes. NO min-waves launch bound: the
// hot shuffles are all mask 1/2/4 (DPP, low latency) so this kernel wants
// VGPRs/ILP, not occupancy. round-3's (256,4) bound + unroll caused a 32-VGPR
// spill-fest (WRITE_SIZE +17MB of scratch, 152us); this restores headroom.
// blockCounts layout TRANSPOSED: [expert][block] so K2 is coalesced.
// ---------------------------------------------------------------------------
__global__ __launch_bounds__(256) void topk_kernel(
    const float* __restrict__ logits,
    float* __restrict__ out_scores,
    float* __restrict__ out_assign,
    float* __restrict__ out_logits,
    int* __restrict__ blockCounts)      // ws: [NE][NBLK]
{
    __shared__ int wcnt[4][NE];          // 1 KB, per-wave histogram rows

    const int t = threadIdx.x;
    const int b = blockIdx.x;
    const int g = t & 7;                 // lane within 8-lane token group
    const int tok_in_pass = t >> 3;      // 0..31
    const int w = t >> 6;                // wave 0..3
    const int l = t & 63;                // lane
    const unsigned long long lt_mask = (l == 0) ? 0ull : ((~0ull) >> (64 - l));

    wcnt[w][l] = 0;                      // covers all 4x64 entries
    __syncthreads();                     // barrier 1

    #pragma unroll
    for (int pass = 0; pass < 4; ++pass) {
        const int ltok = pass * 32 + tok_in_pass;       // 0..127
        const int token = b * TPB + ltok;
        const float* lp = logits + (size_t)token * NE + g * 8;
        float4 v0 = *(const float4*)lp;
        float4 v1 = *(const float4*)(lp + 4);
        // passthrough copy
        float* op = out_logits + (size_t)token * NE + g * 8;
        *(float4*)op = v0;
        *(float4*)(op + 4) = v1;

        float lv[8] = {v0.x, v0.y, v0.z, v0.w, v1.x, v1.y, v1.z, v1.w};

        // softmax: max over 64 (local 8 + 3-step shuffle within group of 8)
        float m = lv[0];
        #pragma unroll
        for (int j = 1; j < 8; ++j) m = fmaxf(m, lv[j]);
        #pragma unroll
        for (int sh = 1; sh < 8; sh <<= 1) m = fmaxf(m, __shfl_xor(m, sh, 64));

        float p[8];
        float s = 0.f;
        #pragma unroll
        for (int j = 0; j < 8; ++j) { p[j] = expf(lv[j] - m); s += p[j]; }
        #pragma unroll
        for (int sh = 1; sh < 8; sh <<= 1) s += __shfl_xor(s, sh, 64);
        // one IEEE div + 8 muls instead of 8 divs: <=1 ulp vs p[j]/s,
        // three orders of magnitude under the >=2^-10 harness tolerance.
        const float rs = 1.0f / s;
        #pragma unroll
        for (int j = 0; j < 8; ++j) p[j] = p[j] * rs;

        // iterative top-8 on probs; tie -> smaller global index
        float sc = 0.f; int id = 0;
        #pragma unroll
        for (int k = 0; k < NK; ++k) {
            float bv = p[0]; int bi = 0;
            #pragma unroll
            for (int j = 1; j < 8; ++j)
                if (p[j] > bv) { bv = p[j]; bi = j; }   // strict > keeps low idx
            int bidx = g * 8 + bi;
            #pragma unroll
            for (int sh = 1; sh < 8; sh <<= 1) {
                float ov = __shfl_xor(bv, sh, 64);
                int   oi = __shfl_xor(bidx, sh, 64);
                if (ov > bv || (ov == bv && oi < bidx)) { bv = ov; bidx = oi; }
            }
            if (g == k) { sc = bv; id = bidx; }
            if ((bidx >> 3) == g) p[bidx & 7] = -1.0f;  // kill winner
        }

        const size_t slot = (size_t)token * NK + g;     // coalesced
        out_scores[slot] = sc;
        out_assign[slot] = (float)id;

        // histogram: ballot-match, leader accumulates its group's count
        const int e = id;
        unsigned long long mask = ~0ull;
        #pragma unroll
        for (int bit = 0; bit < 6; ++bit) {
            unsigned long long bb = __ballot((e >> bit) & 1);
            mask &= ((e >> bit) & 1) ? bb : ~bb;
        }
        if ((mask & lt_mask) == 0ull)
            atomicAdd(&wcnt[w][e], __popcll(mask));     // leader only
    }

    __syncthreads();                     // barrier 2
    if (t < NE) {
        const int c = wcnt[0][t] + wcnt[1][t] + wcnt[2][t] + wcnt[3][t];
        blockCounts[t * NBLK + b] = c;   // transposed layout
    }
}

// ---------------------------------------------------------------------------
// Kernel 2: per-expert exclusive prefix sum over 4096 block counts
// (in place -> block starts). One block per expert; transposed layout makes
// every global access fully coalesced. LDS staging padded (j + j/16) to
// avoid 16-int-stride bank conflicts. Totals -> counts output.
// ---------------------------------------------------------------------------
__global__ __launch_bounds__(256) void scan_kernel(
    int* __restrict__ blockCounts, float* __restrict__ out_counts)
{
    __shared__ int buf[NBLK + (NBLK >> 4)];   // 4352 ints = 17 KB
    __shared__ int part[256];
    const int e = blockIdx.x;            // 0..63
    const int t = threadIdx.x;           // 0..255
    int* col = blockCounts + (size_t)e * NBLK;

    #pragma unroll
    for (int i = 0; i < 16; ++i) {
        const int j = i * 256 + t;       // coalesced global read
        buf[j + (j >> 4)] = col[j];
    }
    __syncthreads();

    int loc[16];
    int s = 0;
    #pragma unroll
    for (int i = 0; i < 16; ++i) {       // thread t owns blocks [16t, 16t+16)
        const int j = t * 16 + i;
        loc[i] = s;
        s += buf[j + (j >> 4)];
    }
    part[t] = s;
    __syncthreads();

    // Hillis-Steele inclusive scan over 256 partials
    for (int off = 1; off < 256; off <<= 1) {
        int v = (t >= off) ? part[t - off] : 0;
        __syncthreads();
        part[t] += v;
        __syncthreads();
    }
    const int run = (t == 0) ? 0 : part[t - 1];

    #pragma unroll
    for (int i = 0; i < 16; ++i) {
        const int j = t * 16 + i;
        buf[j + (j >> 4)] = run + loc[i];    // exclusive start per block
    }
    __syncthreads();
    #pragma unroll
    for (int i = 0; i < 16; ++i) {
        const int j = i * 256 + t;
        col[j] = buf[j + (j >> 4)];      // coalesced global write
    }
    if (t == 255) out_counts[e] = (float)part[255];
}

// ---------------------------------------------------------------------------
// Kernel 3: recompute stable in-block ranks from out_assign and write final
// offsets. TWO barriers. All 4 tiles loaded first (masks kept in registers),
// leaders atomic-accumulate cnt[tile][wave][e], one barrier, then all ranks
// computed as LDS prefix sums and streamed out.
// ---------------------------------------------------------------------------
__global__ __launch_bounds__(256) void offs_kernel(
    const int* __restrict__ blockCounts,   // [NE][NBLK] scanned starts
    const float* __restrict__ out_assign,
    float* __restrict__ out_offs)
{
    __shared__ int cnt[4][4][NE];        // [tile][wave][expert], 4 KB
    __shared__ int base[NE];
    const int t = threadIdx.x;
    const int b = blockIdx.x;
    const int w = t >> 6;                // wave 0..3
    const int l = t & 63;                // lane
    const unsigned long long lt_mask = (l == 0) ? 0ull : ((~0ull) >> (64 - l));

    #pragma unroll
    for (int tau = 0; tau < 4; ++tau) cnt[tau][w][l] = 0;
    if (t < NE) base[t] = blockCounts[t * NBLK + b];
    __syncthreads();                     // barrier 1

    int e_r[4];
    unsigned long long mask_r[4];
    #pragma unroll
    for (int tau = 0; tau < 4; ++tau) {
        const int gslot = b * SPB + tau * 256 + t;     // token-major order
        const int e = (int)out_assign[gslot];
        e_r[tau] = e;
        unsigned long long mask = ~0ull;
        #pragma unroll
        for (int bit = 0; bit < 6; ++bit) {
            unsigned long long bb = __ballot((e >> bit) & 1);
            mask &= ((e >> bit) & 1) ? bb : ~bb;
        }
        mask_r[tau] = mask;
        if ((mask & lt_mask) == 0ull)
            atomicAdd(&cnt[tau][w][e], __popcll(mask));  // leader only
    }
    __syncthreads();                     // barrier 2

    #pragma unroll
    for (int tau = 0; tau < 4; ++tau) {
        const int e = e_r[tau];
        int before = base[e];
        #pragma unroll
        for (int tau2 = 0; tau2 < 4; ++tau2)
            if (tau2 < tau)
                before += cnt[tau2][0][e] + cnt[tau2][1][e]
                        + cnt[tau2][2][e] + cnt[tau2][3][e];
        if (w > 0) before += cnt[tau][0][e];
        if (w > 1) before += cnt[tau][1][e];
        if (w > 2) before += cnt[tau][2][e];
        const int gslot = b * SPB + tau * 256 + t;
        out_offs[gslot] = (float)(before + __popcll(mask_r[tau] & lt_mask));
    }
}

extern "C" void kernel_launch(void* const* d_in, const int* in_sizes, int n_in,
                              void* d_out, int out_size, void* d_ws, size_t ws_size,
                              hipStream_t stream) {
    // inputs: [0] expert_counts placeholder, [1] assignments placeholder,
    //         [2] offsets placeholder, [3] logits [NT, NE] float32
    const float* logits = (const float*)d_in[3];

    float* out = (float*)d_out;
    float* out_counts = out;                                   // [64]
    float* out_scores = out + NE;                              // [NT*NK]
    float* out_assign = out_scores + (size_t)NT * NK;          // [NT*NK]
    float* out_offs   = out_assign + (size_t)NT * NK;          // [NT*NK]
    float* out_logits = out_offs + (size_t)NT * NK;            // [NT*NE]

    int* blockCounts = (int*)d_ws;                             // 64*4096*4 = 1 MB

    hipLaunchKernelGGL(topk_kernel, dim3(NBLK), dim3(256), 0, stream,
                       logits, out_scores, out_assign, out_logits, blockCounts);
    hipLaunchKernelGGL(scan_kernel, dim3(NE), dim3(256), 0, stream,
                       blockCounts, out_counts);
    hipLaunchKernelGGL(offs_kernel, dim3(NBLK), dim3(256), 0, stream,
                       blockCounts, out_assign, out_offs);
}